// Round 1
// baseline (163.335 us; speedup 1.0000x reference)
//
#include <hip/hip_runtime.h>
#include <hip/hip_bf16.h>
#include <cstdint>

#define NHEAD 8
#define HD 32
#define DM 256
#define HH 56
#define WWID 56
#define HW 3136          // 56*56
#define NB 2
#define SCALE 0.17677669529663687f   // 32^-0.5

typedef unsigned int u32;

#define BF2F_LO(u) __uint_as_float((u) << 16)
#define BF2F_HI(u) __uint_as_float((u) & 0xffff0000u)

// ---------------------------------------------------------------------------
// Stage 1: q/k/v = W x + b  (per batch GEMM M=256, N=3136, K=256)
// x: [B, 256, 3136] fp32.  Output layout: [b, head, pos, d] bf16 (d contiguous).
// 64x64 block tile, 256 threads, 4x4 micro-tile, BK=16.
// ---------------------------------------------------------------------------
__global__ __launch_bounds__(256) void qkv_proj(
    const float* __restrict__ x,
    const float* __restrict__ wq, const float* __restrict__ bq,
    const float* __restrict__ wk, const float* __restrict__ bk,
    const float* __restrict__ wv, const float* __restrict__ bv,
    __hip_bfloat16* __restrict__ qo, __hip_bfloat16* __restrict__ ko,
    __hip_bfloat16* __restrict__ vo)
{
    const int zb = blockIdx.z;
    const int b = zb / 3;
    const int proj = zb - 3 * b;
    const float* __restrict__ w  = proj == 0 ? wq : (proj == 1 ? wk : wv);
    const float* __restrict__ bi = proj == 0 ? bq : (proj == 1 ? bk : bv);
    __hip_bfloat16* __restrict__ out = proj == 0 ? qo : (proj == 1 ? ko : vo);

    const int p0 = blockIdx.x * 64;   // position tile (N)
    const int o0 = blockIdx.y * 64;   // out-channel tile (M)
    const float* xb = x + (size_t)b * DM * HW;

    __shared__ float As[16][68];      // [kk][m], pad 68 -> 16B-aligned rows, no conflicts
    __shared__ float Bs[16][64];      // [kk][n]

    const int t = threadIdx.x;
    const int tn = t & 15;
    const int tm = t >> 4;
    float acc[4][4] = {};

    for (int k0 = 0; k0 < DM; k0 += 16) {
        {   // A tile: W[o0+m][k0+kk]  (row-major, K contiguous) -> transposed to As
            const int m  = t >> 2;
            const int kk = (t & 3) << 2;
            float4 a4 = *(const float4*)&w[(size_t)(o0 + m) * DM + k0 + kk];
            As[kk + 0][m] = a4.x; As[kk + 1][m] = a4.y;
            As[kk + 2][m] = a4.z; As[kk + 3][m] = a4.w;
        }
        {   // B tile: X[k0+kk][p0+n] (N contiguous, coalesced float4)
            const int kk = t >> 4;
            const int n  = (t & 15) << 2;
            *(float4*)&Bs[kk][n] = *(const float4*)&xb[(size_t)(k0 + kk) * HW + p0 + n];
        }
        __syncthreads();
        #pragma unroll
        for (int kk = 0; kk < 16; ++kk) {
            float4 a4 = *(const float4*)&As[kk][tm << 2];
            float4 b4 = *(const float4*)&Bs[kk][tn << 2];
            float ar[4] = {a4.x, a4.y, a4.z, a4.w};
            float br[4] = {b4.x, b4.y, b4.z, b4.w};
            #pragma unroll
            for (int i = 0; i < 4; ++i)
                #pragma unroll
                for (int j = 0; j < 4; ++j)
                    acc[i][j] = fmaf(ar[i], br[j], acc[i][j]);
        }
        __syncthreads();
    }

    // epilogue -> out[((b*8+h)*HW + p)*32 + d], 4 consecutive d per thread (8B stores)
    const int om = o0 + (tm << 2);
    const int h  = om >> 5;
    const int d0 = om & 31;           // multiple of 4, stays inside one head
    float bias4[4] = {bi[om], bi[om + 1], bi[om + 2], bi[om + 3]};
    const size_t rowbase = (size_t)(b * NHEAD + h) * HW * HD + d0;
    #pragma unroll
    for (int j = 0; j < 4; ++j) {
        const int p = p0 + (tn << 2) + j;
        union { ushort4 u; __hip_bfloat16 hx[4]; } pk;
        #pragma unroll
        for (int i = 0; i < 4; ++i)
            pk.hx[i] = __float2bfloat16(acc[i][j] + bias4[i]);
        *(ushort4*)&out[rowbase + (size_t)p * HD] = pk.u;
    }
}

// ---------------------------------------------------------------------------
// Stage 2: sliding-window attention. One thread per (b, head, pos).
// Zero-padding semantics: OOB neighbors contribute score 0 (included in
// softmax denominator) and v=0 (no numerator contribution) — matches ref.
// Writes fp32 out[B, C, HW] (c = head*32 + d).
// ---------------------------------------------------------------------------
__global__ __launch_bounds__(256) void attn_win(
    const __hip_bfloat16* __restrict__ q,
    const __hip_bfloat16* __restrict__ k,
    const __hip_bfloat16* __restrict__ v,
    float* __restrict__ out)
{
    const int gid = blockIdx.x * 256 + threadIdx.x;
    const int bh = gid / HW;
    const int p  = gid - bh * HW;
    const int y  = p / WWID;
    const int x  = p - y * WWID;
    const size_t base = (size_t)bh * HW * HD;

    float qf[32];
    {
        const uint4* qp = (const uint4*)(q + base + (size_t)p * HD);
        #pragma unroll
        for (int c = 0; c < 4; ++c) {
            uint4 u = qp[c];
            qf[c * 8 + 0] = BF2F_LO(u.x); qf[c * 8 + 1] = BF2F_HI(u.x);
            qf[c * 8 + 2] = BF2F_LO(u.y); qf[c * 8 + 3] = BF2F_HI(u.y);
            qf[c * 8 + 4] = BF2F_LO(u.z); qf[c * 8 + 5] = BF2F_HI(u.z);
            qf[c * 8 + 6] = BF2F_LO(u.w); qf[c * 8 + 7] = BF2F_HI(u.w);
        }
    }

    float sc[49];
    #pragma unroll
    for (int i = 0; i < 7; ++i) {
        const int yy = y + i - 3;
        #pragma unroll
        for (int j = 0; j < 7; ++j) {
            const int xx = x + j - 3;
            float s = 0.f;
            if ((unsigned)yy < HH && (unsigned)xx < WWID) {
                const uint4* kp = (const uint4*)(k + base + (size_t)(yy * WWID + xx) * HD);
                #pragma unroll
                for (int c = 0; c < 4; ++c) {
                    uint4 u = kp[c];
                    s = fmaf(BF2F_LO(u.x), qf[c * 8 + 0], s);
                    s = fmaf(BF2F_HI(u.x), qf[c * 8 + 1], s);
                    s = fmaf(BF2F_LO(u.y), qf[c * 8 + 2], s);
                    s = fmaf(BF2F_HI(u.y), qf[c * 8 + 3], s);
                    s = fmaf(BF2F_LO(u.z), qf[c * 8 + 4], s);
                    s = fmaf(BF2F_HI(u.z), qf[c * 8 + 5], s);
                    s = fmaf(BF2F_LO(u.w), qf[c * 8 + 6], s);
                    s = fmaf(BF2F_HI(u.w), qf[c * 8 + 7], s);
                }
            }
            sc[i * 7 + j] = s * SCALE;   // OOB -> exactly 0, included in softmax
        }
    }

    float m = sc[0];
    #pragma unroll
    for (int i = 1; i < 49; ++i) m = fmaxf(m, sc[i]);
    float sum = 0.f;
    #pragma unroll
    for (int i = 0; i < 49; ++i) { sc[i] = __expf(sc[i] - m); sum += sc[i]; }
    const float inv = 1.f / sum;

    float of[32] = {};
    #pragma unroll
    for (int i = 0; i < 7; ++i) {
        const int yy = y + i - 3;
        #pragma unroll
        for (int j = 0; j < 7; ++j) {
            const int xx = x + j - 3;
            if ((unsigned)yy < HH && (unsigned)xx < WWID) {
                const float wgt = sc[i * 7 + j];
                const uint4* vp = (const uint4*)(v + base + (size_t)(yy * WWID + xx) * HD);
                #pragma unroll
                for (int c = 0; c < 4; ++c) {
                    uint4 u = vp[c];
                    of[c * 8 + 0] = fmaf(BF2F_LO(u.x), wgt, of[c * 8 + 0]);
                    of[c * 8 + 1] = fmaf(BF2F_HI(u.x), wgt, of[c * 8 + 1]);
                    of[c * 8 + 2] = fmaf(BF2F_LO(u.y), wgt, of[c * 8 + 2]);
                    of[c * 8 + 3] = fmaf(BF2F_HI(u.y), wgt, of[c * 8 + 3]);
                    of[c * 8 + 4] = fmaf(BF2F_LO(u.z), wgt, of[c * 8 + 4]);
                    of[c * 8 + 5] = fmaf(BF2F_HI(u.z), wgt, of[c * 8 + 5]);
                    of[c * 8 + 6] = fmaf(BF2F_LO(u.w), wgt, of[c * 8 + 6]);
                    of[c * 8 + 7] = fmaf(BF2F_HI(u.w), wgt, of[c * 8 + 7]);
                }
            }
        }
    }
    const size_t ob = (size_t)bh * HD * HW + p;   // out[(bh*32+d)*HW + p]
    #pragma unroll
    for (int d = 0; d < 32; ++d)
        out[ob + (size_t)d * HW] = of[d] * inv;
}

// ---------------------------------------------------------------------------
// Stage 3: final projection, fp32 in / fp32 out to d_out [B, 256, 3136].
// ---------------------------------------------------------------------------
__global__ __launch_bounds__(256) void out_proj(
    const float* __restrict__ attn,   // [B, DM, HW] fp32
    const float* __restrict__ wo, const float* __restrict__ bo,
    float* __restrict__ yout)
{
    const int b  = blockIdx.z;
    const int p0 = blockIdx.x * 64;
    const int o0 = blockIdx.y * 64;
    const float* ab = attn + (size_t)b * DM * HW;

    __shared__ float As[16][68];
    __shared__ float Bs[16][64];

    const int t = threadIdx.x;
    const int tn = t & 15;
    const int tm = t >> 4;
    float acc[4][4] = {};

    for (int k0 = 0; k0 < DM; k0 += 16) {
        {
            const int m  = t >> 2;
            const int kk = (t & 3) << 2;
            float4 a4 = *(const float4*)&wo[(size_t)(o0 + m) * DM + k0 + kk];
            As[kk + 0][m] = a4.x; As[kk + 1][m] = a4.y;
            As[kk + 2][m] = a4.z; As[kk + 3][m] = a4.w;
        }
        {
            const int kk = t >> 4;
            const int n  = (t & 15) << 2;
            *(float4*)&Bs[kk][n] = *(const float4*)&ab[(size_t)(k0 + kk) * HW + p0 + n];
        }
        __syncthreads();
        #pragma unroll
        for (int kk = 0; kk < 16; ++kk) {
            float4 a4 = *(const float4*)&As[kk][tm << 2];
            float4 b4 = *(const float4*)&Bs[kk][tn << 2];
            float ar[4] = {a4.x, a4.y, a4.z, a4.w};
            float br[4] = {b4.x, b4.y, b4.z, b4.w};
            #pragma unroll
            for (int i = 0; i < 4; ++i)
                #pragma unroll
                for (int j = 0; j < 4; ++j)
                    acc[i][j] = fmaf(ar[i], br[j], acc[i][j]);
        }
        __syncthreads();
    }

    #pragma unroll
    for (int i = 0; i < 4; ++i) {
        const int o = o0 + (tm << 2) + i;
        const float bias = bo[o];
        float4 r = make_float4(acc[i][0] + bias, acc[i][1] + bias,
                               acc[i][2] + bias, acc[i][3] + bias);
        *(float4*)&yout[(size_t)(b * DM + o) * HW + p0 + (tn << 2)] = r;
    }
}

// ---------------------------------------------------------------------------
extern "C" void kernel_launch(void* const* d_in, const int* in_sizes, int n_in,
                              void* d_out, int out_size, void* d_ws, size_t ws_size,
                              hipStream_t stream) {
    const float* x  = (const float*)d_in[0];
    const float* wq = (const float*)d_in[1];
    const float* bq = (const float*)d_in[2];
    const float* wk = (const float*)d_in[3];
    const float* bk = (const float*)d_in[4];
    const float* wv = (const float*)d_in[5];
    const float* bv = (const float*)d_in[6];
    const float* wo = (const float*)d_in[7];
    const float* bo = (const float*)d_in[8];
    float* out = (float*)d_out;

    // Workspace layout: q,k,v bf16 [B,8,HW,32] (3 x 3.21 MB) + attn fp32 [B,256,HW] (6.4 MB)
    const size_t QKV = (size_t)NB * NHEAD * HW * HD;   // 1,605,632 elems
    __hip_bfloat16* qb = (__hip_bfloat16*)d_ws;
    __hip_bfloat16* kb = qb + QKV;
    __hip_bfloat16* vb = kb + QKV;
    float* attn = (float*)(vb + QKV);

    qkv_proj<<<dim3(HW / 64, DM / 64, 3 * NB), 256, 0, stream>>>(
        x, wq, bq, wk, bk, wv, bv, qb, kb, vb);
    attn_win<<<dim3((NB * NHEAD * HW) / 256), 256, 0, stream>>>(qb, kb, vb, attn);
    out_proj<<<dim3(HW / 64, DM / 64, NB), 256, 0, stream>>>(attn, wo, bo, out);
}

// Round 2
// 132.481 us; speedup vs baseline: 1.2329x; 1.2329x over previous
//
#include <hip/hip_runtime.h>
#include <hip/hip_bf16.h>
#include <cstdint>

#define NHEAD 8
#define HD 32
#define DM 256
#define HH 56
#define WWID 56
#define HW 3136          // 56*56
#define NB 2
#define SCALE 0.17677669529663687f   // 32^-0.5

typedef unsigned int u32;
typedef __attribute__((ext_vector_type(8))) short short8;   // 8 bf16 = 4 VGPRs
typedef __attribute__((ext_vector_type(4))) float floatx4;

#define BF2F_LO(u) __uint_as_float((u) << 16)
#define BF2F_HI(u) __uint_as_float((u) & 0xffff0000u)

// ---------------------------------------------------------------------------
// Convert all four weight matrices fp32 -> bf16. wq,wk,wv stacked into
// wcat[768][256]; wo into wob[256][256]. 65536 threads x 4 elems.
// ---------------------------------------------------------------------------
__global__ __launch_bounds__(256) void convert_w(
    const float* __restrict__ wq, const float* __restrict__ wk,
    const float* __restrict__ wv, const float* __restrict__ wo,
    __hip_bfloat16* __restrict__ wcat, __hip_bfloat16* __restrict__ wob)
{
    const int gid = blockIdx.x * 256 + threadIdx.x;
    const int idx4 = gid << 2;                 // 0 .. 262140
    const int sel = idx4 >> 16;                // 0..3
    const int off = idx4 & 65535;
    const float* src = sel == 0 ? wq : (sel == 1 ? wk : (sel == 2 ? wv : wo));
    __hip_bfloat16* dst = sel < 3 ? (wcat + (sel << 16) + off) : (wob + off);
    float4 f = *(const float4*)&src[off];
    union { ushort4 u; __hip_bfloat16 s[4]; } pk;
    pk.s[0] = __float2bfloat16(f.x); pk.s[1] = __float2bfloat16(f.y);
    pk.s[2] = __float2bfloat16(f.z); pk.s[3] = __float2bfloat16(f.w);
    *(ushort4*)dst = pk.u;
}

// ---------------------------------------------------------------------------
// Transpose-convert x [b][c][p] fp32 -> xT [b][p][c] bf16 (c contiguous).
// 32x32 tiles; LDS pad 33 -> conflict-free.
// ---------------------------------------------------------------------------
__global__ __launch_bounds__(256) void transpose_x(
    const float* __restrict__ x, __hip_bfloat16* __restrict__ xT)
{
    __shared__ float tile[32][33];
    const int b = blockIdx.z, p0 = blockIdx.x * 32, c0 = blockIdx.y * 32;
    const int tx = threadIdx.x & 31, ty = threadIdx.x >> 5;   // ty in [0,8)
    const float* xb = x + (size_t)b * DM * HW;
    #pragma unroll
    for (int i = 0; i < 4; ++i)
        tile[ty + i * 8][tx] = xb[(size_t)(c0 + ty + i * 8) * HW + p0 + tx];
    __syncthreads();
    __hip_bfloat16* xo = xT + (size_t)b * HW * DM;
    #pragma unroll
    for (int i = 0; i < 4; ++i)
        xo[(size_t)(p0 + ty + i * 8) * DM + c0 + tx] =
            __float2bfloat16(tile[tx][ty + i * 8]);
}

// ---------------------------------------------------------------------------
// MFMA GEMM: C[m][n] = A[m][:] . B[:, n],  A = weights bf16 [M][256] (k-contig),
// B element B[k][n] stored as Bm[b][n][k] (k-contig rows).  BM=128, BN=64,
// BK=32, 256 thr = 4 waves, each wave 64x32 via 4x2 tiles of 16x16x32.
// MODE 0: M=768 fused qkv, epilogue -> q/k/v bf16 [b][h][p][d].
// MODE 1: M=256 out-proj,  epilogue -> fp32 d_out [b][c][p].
// ---------------------------------------------------------------------------
template<int MODE>
__global__ __launch_bounds__(256) void gemm_mfma(
    const __hip_bfloat16* __restrict__ A,
    const __hip_bfloat16* __restrict__ Bm,
    const float* __restrict__ b0, const float* __restrict__ b1,
    const float* __restrict__ b2,
    void* __restrict__ o0, void* __restrict__ o1, void* __restrict__ o2)
{
    const int bb = blockIdx.z;
    const int n0 = blockIdx.x * 64;
    const int m0 = blockIdx.y * 128;
    const __hip_bfloat16* Bb = Bm + (size_t)bb * HW * DM + (size_t)n0 * DM;

    __shared__ __align__(16) __hip_bfloat16 As[128][40];  // [m][k], pad 40
    __shared__ __align__(16) __hip_bfloat16 Bs[64][40];   // [n][k]

    const int t = threadIdx.x;
    const int wave = t >> 6, lane = t & 63;
    const int quad = lane >> 4, l16 = lane & 15;
    const int mw = (wave & 1) * 64, nw = (wave >> 1) * 32;

    floatx4 acc[4][2] = {};

    // staging maps (16B chunks)
    const int am = t >> 2, ak = (t & 3) << 3;     // A chunks t and t+256
    const int bn = t >> 2, bk = (t & 3) << 3;     // B chunk t

    for (int k0g = 0; k0g < DM; k0g += 32) {
        *(uint4*)&As[am][ak]      = *(const uint4*)&A[(size_t)(m0 + am) * DM + k0g + ak];
        *(uint4*)&As[am + 64][ak] = *(const uint4*)&A[(size_t)(m0 + am + 64) * DM + k0g + ak];
        *(uint4*)&Bs[bn][bk]      = *(const uint4*)&Bb[(size_t)bn * DM + k0g + bk];
        __syncthreads();
        short8 af[4], bf[2];
        #pragma unroll
        for (int mt = 0; mt < 4; ++mt)
            af[mt] = *(const short8*)&As[mw + mt * 16 + l16][quad * 8];
        #pragma unroll
        for (int nt = 0; nt < 2; ++nt)
            bf[nt] = *(const short8*)&Bs[nw + nt * 16 + l16][quad * 8];
        #pragma unroll
        for (int mt = 0; mt < 4; ++mt)
            #pragma unroll
            for (int nt = 0; nt < 2; ++nt)
                acc[mt][nt] = __builtin_amdgcn_mfma_f32_16x16x32_bf16(
                    af[mt], bf[nt], acc[mt][nt], 0, 0, 0);
        __syncthreads();
    }

    // D layout: row(m) = quad*4 + r, col(n) = l16 within each 16x16 tile.
    if (MODE == 0) {
        #pragma unroll
        for (int mt = 0; mt < 4; ++mt) {
            const int gm = m0 + mw + mt * 16 + quad * 4;   // global row, r adds 0..3
            const int proj = gm >> 8;
            const int c = gm & 255;
            const int h = c >> 5, d0 = c & 31;
            const float* bptr = proj == 0 ? b0 : (proj == 1 ? b1 : b2);
            __hip_bfloat16* op = (__hip_bfloat16*)(proj == 0 ? o0 : (proj == 1 ? o1 : o2));
            const size_t base = ((size_t)(bb * NHEAD + h) * HW) * HD + d0;
            float bias[4] = {bptr[c], bptr[c + 1], bptr[c + 2], bptr[c + 3]};
            #pragma unroll
            for (int nt = 0; nt < 2; ++nt) {
                const int p = n0 + nw + nt * 16 + l16;
                union { ushort4 u; __hip_bfloat16 s[4]; } pk;
                #pragma unroll
                for (int r = 0; r < 4; ++r)
                    pk.s[r] = __float2bfloat16(acc[mt][nt][r] + bias[r]);
                *(ushort4*)&op[base + (size_t)p * HD] = pk.u;
            }
        }
    } else {
        float* yo = (float*)o0;
        #pragma unroll
        for (int mt = 0; mt < 4; ++mt) {
            const int gc = m0 + mw + mt * 16 + quad * 4;
            #pragma unroll
            for (int r = 0; r < 4; ++r) {
                const float bias = b0[gc + r];
                #pragma unroll
                for (int nt = 0; nt < 2; ++nt) {
                    const int p = n0 + nw + nt * 16 + l16;
                    yo[(size_t)(bb * DM + gc + r) * HW + p] = acc[mt][nt][r] + bias;
                }
            }
        }
    }
}

// ---------------------------------------------------------------------------
// Stage 2: sliding-window attention, one thread per (b, head, pos).
// Zero-padding: OOB scores = 0 INCLUDED in softmax (matches reference).
// Output bf16 attnT[b][p][c] (c contiguous) -> out-proj B operand layout.
// ---------------------------------------------------------------------------
__global__ __launch_bounds__(256) void attn_win(
    const __hip_bfloat16* __restrict__ q,
    const __hip_bfloat16* __restrict__ k,
    const __hip_bfloat16* __restrict__ v,
    __hip_bfloat16* __restrict__ out)
{
    const int gid = blockIdx.x * 256 + threadIdx.x;
    const int bh = gid / HW;
    const int p  = gid - bh * HW;
    const int y  = p / WWID;
    const int x  = p - y * WWID;
    const size_t base = (size_t)bh * HW * HD;

    float qf[32];
    {
        const uint4* qp = (const uint4*)(q + base + (size_t)p * HD);
        #pragma unroll
        for (int c = 0; c < 4; ++c) {
            uint4 u = qp[c];
            qf[c * 8 + 0] = BF2F_LO(u.x); qf[c * 8 + 1] = BF2F_HI(u.x);
            qf[c * 8 + 2] = BF2F_LO(u.y); qf[c * 8 + 3] = BF2F_HI(u.y);
            qf[c * 8 + 4] = BF2F_LO(u.z); qf[c * 8 + 5] = BF2F_HI(u.z);
            qf[c * 8 + 6] = BF2F_LO(u.w); qf[c * 8 + 7] = BF2F_HI(u.w);
        }
    }

    float sc[49];
    #pragma unroll
    for (int i = 0; i < 7; ++i) {
        const int yy = y + i - 3;
        #pragma unroll
        for (int j = 0; j < 7; ++j) {
            const int xx = x + j - 3;
            float s = 0.f;
            if ((unsigned)yy < HH && (unsigned)xx < WWID) {
                const uint4* kp = (const uint4*)(k + base + (size_t)(yy * WWID + xx) * HD);
                #pragma unroll
                for (int c = 0; c < 4; ++c) {
                    uint4 u = kp[c];
                    s = fmaf(BF2F_LO(u.x), qf[c * 8 + 0], s);
                    s = fmaf(BF2F_HI(u.x), qf[c * 8 + 1], s);
                    s = fmaf(BF2F_LO(u.y), qf[c * 8 + 2], s);
                    s = fmaf(BF2F_HI(u.y), qf[c * 8 + 3], s);
                    s = fmaf(BF2F_LO(u.z), qf[c * 8 + 4], s);
                    s = fmaf(BF2F_HI(u.z), qf[c * 8 + 5], s);
                    s = fmaf(BF2F_LO(u.w), qf[c * 8 + 6], s);
                    s = fmaf(BF2F_HI(u.w), qf[c * 8 + 7], s);
                }
            }
            sc[i * 7 + j] = s * SCALE;
        }
    }

    float m = sc[0];
    #pragma unroll
    for (int i = 1; i < 49; ++i) m = fmaxf(m, sc[i]);
    float sum = 0.f;
    #pragma unroll
    for (int i = 0; i < 49; ++i) { sc[i] = __expf(sc[i] - m); sum += sc[i]; }
    const float inv = 1.f / sum;

    float of[32] = {};
    #pragma unroll
    for (int i = 0; i < 7; ++i) {
        const int yy = y + i - 3;
        #pragma unroll
        for (int j = 0; j < 7; ++j) {
            const int xx = x + j - 3;
            if ((unsigned)yy < HH && (unsigned)xx < WWID) {
                const float wgt = sc[i * 7 + j];
                const uint4* vp = (const uint4*)(v + base + (size_t)(yy * WWID + xx) * HD);
                #pragma unroll
                for (int c = 0; c < 4; ++c) {
                    uint4 u = vp[c];
                    of[c * 8 + 0] = fmaf(BF2F_LO(u.x), wgt, of[c * 8 + 0]);
                    of[c * 8 + 1] = fmaf(BF2F_HI(u.x), wgt, of[c * 8 + 1]);
                    of[c * 8 + 2] = fmaf(BF2F_LO(u.y), wgt, of[c * 8 + 2]);
                    of[c * 8 + 3] = fmaf(BF2F_HI(u.y), wgt, of[c * 8 + 3]);
                    of[c * 8 + 4] = fmaf(BF2F_LO(u.z), wgt, of[c * 8 + 4]);
                    of[c * 8 + 5] = fmaf(BF2F_HI(u.z), wgt, of[c * 8 + 5]);
                    of[c * 8 + 6] = fmaf(BF2F_LO(u.w), wgt, of[c * 8 + 6]);
                    of[c * 8 + 7] = fmaf(BF2F_HI(u.w), wgt, of[c * 8 + 7]);
                }
            }
        }
    }

    // write attnT[b][p][h*32+d], 4 x 16B contiguous stores
    const int b = bh >> 3, h = bh & 7;
    __hip_bfloat16* op = out + ((size_t)b * HW + p) * DM + h * HD;
    #pragma unroll
    for (int c = 0; c < 4; ++c) {
        union { uint4 u; __hip_bfloat16 s[8]; } pk;
        #pragma unroll
        for (int j = 0; j < 8; ++j)
            pk.s[j] = __float2bfloat16(of[c * 8 + j] * inv);
        *(uint4*)&op[c * 8] = pk.u;
    }
}

// ---------------------------------------------------------------------------
extern "C" void kernel_launch(void* const* d_in, const int* in_sizes, int n_in,
                              void* d_out, int out_size, void* d_ws, size_t ws_size,
                              hipStream_t stream) {
    const float* x  = (const float*)d_in[0];
    const float* wq = (const float*)d_in[1];
    const float* bq = (const float*)d_in[2];
    const float* wk = (const float*)d_in[3];
    const float* bk = (const float*)d_in[4];
    const float* wv = (const float*)d_in[5];
    const float* bv = (const float*)d_in[6];
    const float* wo = (const float*)d_in[7];
    const float* bo = (const float*)d_in[8];
    float* out = (float*)d_out;

    const size_t NPC = (size_t)NB * HW * DM;     // 1,605,632 elems
    __hip_bfloat16* xT   = (__hip_bfloat16*)d_ws;          // [b][p][c]
    __hip_bfloat16* wcat = xT + NPC;                       // [768][256]
    __hip_bfloat16* wob  = wcat + 768 * 256;               // [256][256]
    __hip_bfloat16* qb   = wob + 256 * 256;                // [b][h][p][d]
    __hip_bfloat16* kb   = qb + NPC;
    __hip_bfloat16* vb   = kb + NPC;
    __hip_bfloat16* attnT = vb + NPC;                      // [b][p][c]

    convert_w<<<256, 256, 0, stream>>>(wq, wk, wv, wo, wcat, wob);
    transpose_x<<<dim3(HW / 32, DM / 32, NB), 256, 0, stream>>>(x, xT);
    gemm_mfma<0><<<dim3(HW / 64, 6, NB), 256, 0, stream>>>(
        wcat, xT, bq, bk, bv, qb, kb, vb);
    attn_win<<<dim3((NB * NHEAD * HW) / 256), 256, 0, stream>>>(qb, kb, vb, attnT);
    gemm_mfma<1><<<dim3(HW / 64, 2, NB), 256, 0, stream>>>(
        wob, attnT, bo, bo, bo, out, out, out);
}